// Round 14
// baseline (271.100 us; speedup 1.0000x reference)
//
#include <hip/hip_runtime.h>
#include <hip/hip_bf16.h>
#include <stdint.h>

typedef __bf16 bf16x8 __attribute__((ext_vector_type(8)));
typedef float f32x4 __attribute__((ext_vector_type(4)));
typedef unsigned short u16;
typedef u16 u16x4 __attribute__((ext_vector_type(4)));

#define S_LEN 2048
#define DMODEL 2048
#define NHEADS 32
#define BATCH 2
#define MROWS (BATCH * S_LEN)   // 4096
#define BIAS_LEN 1024
#define LOG2E 1.44269504088896f

__device__ __forceinline__ u16 b16(float f) {
  union { __bf16 h; u16 u; } cv; cv.h = (__bf16)f; return cv.u;
}

__device__ __forceinline__ void gload16(const void* g, void* l) {
  __builtin_amdgcn_global_load_lds(
      (const __attribute__((address_space(1))) uint32_t*)g,
      (__attribute__((address_space(3))) uint32_t*)l, 16, 0, 0);
}

// ---------------- fused prep: hs->bf16, 4xW->bf16, rope tables, bias ------
__global__ __launch_bounds__(256)
void prep_all(const float* __restrict__ hs,
              const float* __restrict__ w0, const float* __restrict__ w1,
              const float* __restrict__ w2, const float* __restrict__ w3,
              const float* __restrict__ bias,
              u16* __restrict__ hs_b, u16* __restrict__ w_b,
              float* __restrict__ ct, float* __restrict__ st,
              u16* __restrict__ b16t)
{
  const int blk = blockIdx.x;
  if (blk < 8192) {                      // hs: 8M f32 -> bf16
    int i = (blk * 256 + threadIdx.x) * 4;
    float4 v = *(const float4*)(hs + i);
    u16x4 o = { b16(v.x), b16(v.y), b16(v.z), b16(v.w) };
    *(u16x4*)(hs_b + i) = o;
  } else if (blk < 24576) {              // 4 weight matrices
    int r = blk - 8192;
    int which = r >> 12;
    const float* src = (which == 0) ? w0 : (which == 1) ? w1
                     : (which == 2) ? w2 : w3;
    int i = ((r & 4095) * 256 + threadIdx.x) * 4;
    float4 v = *(const float4*)(src + i);
    u16x4 o = { b16(v.x), b16(v.y), b16(v.z), b16(v.w) };
    *(u16x4*)(w_b + (size_t)which * DMODEL * DMODEL + i) = o;
  } else if (blk < 24832) {              // rope cos/sin [S][32]
    int idx = (blk - 24576) * 256 + threadIdx.x;
    int s = idx >> 5, d = idx & 31;
    float inv = exp2f((float)d * (-13.287712379549449f / 32.0f));
    float a = (float)s * inv;
    ct[idx] = cosf(a);
    st[idx] = sinf(a);
  } else {                               // bias -> bf16 * log2e
    int i = (blk - 24832) * 256 + threadIdx.x;
    b16t[i] = b16(bias[i] * LOG2E);
  }
}

// ================= 8-phase 256x256 Q+K GEMM (T2+T3+T4+T5) =================
// Grid 256 = one tail-free dispatch round at 1 block/CU (128 KB LDS).
// THIS ROUND: template-faithful per-phase DOUBLE barriers (lockstep):
//   {ds_read frags ; stage ; BARR ; lgkmcnt(0) ; 16 MFMA ; BARR}
// Stage order & counted vmcnt unchanged (verified R9/R13).  Barrier
// insertion only: block-uniform control flow -> race/deadlock-free.
#define NT 32   // K tiles = 2048/64

#define STG_A(buf, h, t) { \
    gload16(aS0 + (size_t)(h) * 128 * DMODEL + (t) * 64, (char*)sA[buf][h] + tid * 16); \
    gload16(aS0 + (size_t)((h) * 128 + 64) * DMODEL + (t) * 64, (char*)sA[buf][h] + (512 + tid) * 16); }
#define STG_B(buf, h, t) { \
    gload16(bS0 + (size_t)(h) * 128 * DMODEL + (t) * 64, (char*)sB[buf][h] + tid * 16); \
    gload16(bS0 + (size_t)((h) * 128 + 64) * DMODEL + (t) * 64, (char*)sB[buf][h] + (512 + tid) * 16); }
#define LOAD_B(b, kk) { _Pragma("unroll") \
    for (int ni = 0; ni < 4; ++ni) \
      bq[ni] = *(const bf16x8*)((const char*)sB[b][wn >> 1] + offB[ni][kk]); }
#define LOAD_A(b, q, kk) { _Pragma("unroll") \
    for (int mi = 0; mi < 4; ++mi) \
      af[mi] = *(const bf16x8*)((const char*)sA[b][wm] + offA[q][mi][kk]); }
#define MFMA16(q) { __builtin_amdgcn_s_setprio(1); \
    _Pragma("unroll") for (int mi = 0; mi < 4; ++mi) \
      _Pragma("unroll") for (int ni = 0; ni < 4; ++ni) \
        acc[(q) * 4 + mi][ni] = __builtin_amdgcn_mfma_f32_16x16x32_bf16( \
            af[mi], bq[ni], acc[(q) * 4 + mi][ni], 0, 0, 0); \
    __builtin_amdgcn_s_setprio(0); }
#define LGKM { asm volatile("s_waitcnt lgkmcnt(0)" ::: "memory"); \
               __builtin_amdgcn_sched_barrier(0); }
#define BARR { __builtin_amdgcn_s_barrier(); __builtin_amdgcn_sched_barrier(0); }
#define VM2 { asm volatile("s_waitcnt vmcnt(2)" ::: "memory"); \
              __builtin_amdgcn_sched_barrier(0); }
#define VM0 { asm volatile("s_waitcnt vmcnt(0)" ::: "memory"); \
              __builtin_amdgcn_sched_barrier(0); }

__global__ __launch_bounds__(512, 2)
void gemm_qk8(const u16* __restrict__ A, const u16* __restrict__ W,
              u16* __restrict__ qf, u16* __restrict__ kf,
              const float* __restrict__ ctab, const float* __restrict__ stab)
{
  __shared__ u16 sA[2][2][128 * 64];
  __shared__ u16 sB[2][2][128 * 64];
  const int tid = threadIdx.x, lane = tid & 63, wid = tid >> 6;
  const int wm = wid >> 2, wn = wid & 3;     // 2M x 4N wave grid
  const int lc = lane & 15, lr = lane >> 4;
  const int L = blockIdx.x;
  const int which = L >> 7;                   // 0=q 1=k
  const int rr = L & 127;
  const int tmi = rr >> 3, tni = rr & 7;      // tni == L%8: B-panel L2 pin
  const size_t tm = (size_t)tmi * 256, tn = (size_t)tni * 256;
  const u16* Bm = W + (size_t)which * DMODEL * DMODEL;

  const int r0 = tid >> 3, c0 = (tid & 7) ^ (r0 & 7);
  const u16* aS0 = A  + (tm + r0) * DMODEL + c0 * 8;
  const u16* bS0 = Bm + (tn + r0) * DMODEL + c0 * 8;

  int offA[2][4][2], offB[4][2];
#pragma unroll
  for (int q = 0; q < 2; ++q)
#pragma unroll
    for (int mi = 0; mi < 4; ++mi) {
      int row = q * 64 + mi * 16 + lc;
#pragma unroll
      for (int kk = 0; kk < 2; ++kk)
        offA[q][mi][kk] = row * 128 + ((kk * 4 + lr) ^ (row & 7)) * 16;
    }
#pragma unroll
  for (int ni = 0; ni < 4; ++ni) {
    int row = (wn & 1) * 64 + ni * 16 + lc;
#pragma unroll
    for (int kk = 0; kk < 2; ++kk)
      offB[ni][kk] = row * 128 + ((kk * 4 + lr) ^ (row & 7)) * 16;
  }

  f32x4 acc[8][4] = {};
  bf16x8 af[4], bq[4];

  // prologue: tile0 full + tile1's B-h0 (10 loads); tile0 landed after VM2
  STG_B(0, 0, 0); STG_B(0, 1, 0); STG_A(0, 0, 0); STG_A(0, 1, 0); STG_B(1, 0, 1);
  VM2; BARR;

  for (int i = 0; i < NT / 2; ++i) {
    const int t1 = 2 * i + 1, t2 = 2 * i + 2, t3 = 2 * i + 3;
    // P1 (b0,q0,kk0)
    LOAD_B(0, 0); LOAD_A(0, 0, 0); STG_B(1, 1, t1); BARR; LGKM; MFMA16(0); BARR;
    // P2 (b0,q1,kk0)
    LOAD_A(0, 1, 0); STG_A(1, 0, t1); BARR; LGKM; MFMA16(1); BARR;
    // P3 (b0,q0,kk1)
    LOAD_B(0, 1); LOAD_A(0, 0, 1); STG_A(1, 1, t1); BARR; LGKM; MFMA16(0); BARR;
    // P4 (b0,q1,kk1)  — after this, B(t0)+A(t0) fully consumed; t1 landed
    LOAD_A(0, 1, 1); if (t2 < NT) STG_B(0, 0, t2); BARR; LGKM; MFMA16(1);
    if (t2 < NT) { VM2; } else { VM0; }
    BARR;
    // P5 (b1,q0,kk0)
    LOAD_B(1, 0); LOAD_A(1, 0, 0); if (t2 < NT) STG_B(0, 1, t2); BARR; LGKM; MFMA16(0); BARR;
    // P6 (b1,q1,kk0)
    LOAD_A(1, 1, 0); if (t2 < NT) STG_A(0, 0, t2); BARR; LGKM; MFMA16(1); BARR;
    // P7 (b1,q0,kk1)
    LOAD_B(1, 1); LOAD_A(1, 0, 1); if (t2 < NT) STG_A(0, 1, t2); BARR; LGKM; MFMA16(0); BARR;
    // P8 (b1,q1,kk1) — after this, B(t1)+A(t1) consumed; t2 landed
    LOAD_A(1, 1, 1); if (t3 < NT) STG_B(1, 0, t3); BARR; LGKM; MFMA16(1);
    if (t3 < NT) { VM2; } else { VM0; }
    BARR;
  }

  // epilogue: RoPE (q also * 0.125*log2e), store [B,H,S,D] bf16
  u16* C = (which == 0) ? qf : kf;
  const float scl = (which == 0) ? 0.125f * LOG2E : 1.0f;
#pragma unroll
  for (int q = 0; q < 2; ++q)
#pragma unroll
    for (int mi = 0; mi < 4; ++mi)
#pragma unroll
      for (int ni = 0; ni < 2; ++ni)
#pragma unroll
        for (int j = 0; j < 4; ++j) {
          int col = (int)tn + wn * 64 + ni * 16 + lc;
          int hh = col >> 6, dl = col & 63;     // dl in [0,32)
          int r = (int)tm + wm * 128 + q * 64 + mi * 16 + lr * 4 + j;
          int bb = r >> 11, s = r & 2047;
          float x1 = acc[q * 4 + mi][ni][j], x2 = acc[q * 4 + mi][ni + 2][j];
          float cv = ctab[s * 32 + dl], sv = stab[s * 32 + dl];
          float o1 = (x1 * cv - x2 * sv) * scl;
          float o2 = (x1 * sv + x2 * cv) * scl;
          size_t base = (((size_t)bb * NHEADS + hh) * S_LEN + s) * 64 + dl;
          C[base]      = b16(o1);
          C[base + 32] = b16(o2);
        }
}

// ======== shared 128^2 GEMM main-loop macro (m97 structure) ========
#define GEMM_MAIN_LOOP(Aptr, Bptr)                                            \
  f32x4 acc[4][4] = {};                                                       \
  const u16* aS[4]; const u16* bS[4];                                         \
  _Pragma("unroll")                                                           \
  for (int it = 0; it < 4; ++it) {                                            \
    int u = it * 256 + tid;                                                   \
    int row = u >> 3;                                                         \
    int ch  = (u & 7) ^ (row & 7);                                            \
    aS[it] = (Aptr) + (size_t)(tm + row) * DMODEL + ch * 8;                   \
    bS[it] = (Bptr) + (size_t)(tn + row) * DMODEL + ch * 8;                   \
  }                                                                           \
  for (int k0 = 0; k0 < DMODEL; k0 += 64) {                                   \
    __syncthreads();                                                          \
    _Pragma("unroll")                                                         \
    for (int it = 0; it < 4; ++it) {                                          \
      int u = it * 256 + tid;                                                 \
      gload16(aS[it] + k0, (char*)sA + u * 16);                               \
      gload16(bS[it] + k0, (char*)sB + u * 16);                               \
    }                                                                         \
    __syncthreads();                                                          \
    _Pragma("unroll")                                                         \
    for (int kk = 0; kk < 2; ++kk) {                                          \
      bf16x8 af[4], bq[4];                                                    \
      _Pragma("unroll")                                                       \
      for (int mi = 0; mi < 4; ++mi) {                                        \
        int row = wm * 64 + mi * 16 + lc;                                     \
        int ch  = (kk * 4 + lr) ^ (row & 7);                                  \
        af[mi] = *(const bf16x8*)((const char*)sA + row * 128 + ch * 16);     \
      }                                                                       \
      _Pragma("unroll")                                                       \
      for (int ni = 0; ni < 4; ++ni) {                                        \
        int row = wn * 64 + ni * 16 + lc;                                     \
        int ch  = (kk * 4 + lr) ^ (row & 7);                                  \
        bq[ni] = *(const bf16x8*)((const char*)sB + row * 128 + ch * 16);     \
      }                                                                       \
      _Pragma("unroll")                                                       \
      for (int mi = 0; mi < 4; ++mi)                                          \
        _Pragma("unroll")                                                     \
        for (int ni = 0; ni < 4; ++ni)                                        \
          acc[mi][ni] = __builtin_amdgcn_mfma_f32_16x16x32_bf16(              \
              af[mi], bq[ni], acc[mi][ni], 0, 0, 0);                          \
    }                                                                         \
  }

// ---------------- V projection GEMM (128^2, XCD-swizzled, v^T store) -----
__global__ __launch_bounds__(256)
void gemm_v(const u16* __restrict__ A, const u16* __restrict__ Bm,
            u16* __restrict__ vt)
{
  __shared__ u16 sA[128 * 64];
  __shared__ u16 sB[128 * 64];
  const int tid  = threadIdx.x;
  const int lane = tid & 63;
  const int wid  = tid >> 6;
  const int wm   = wid >> 1, wn = wid & 1;
  const int lc   = lane & 15, lr = lane >> 4;
  const int L = blockIdx.x;                   // 512 blocks
  const int r = L >> 3;                       // 0..63
  const int x = (L & 7) * 2 + (r & 1);        // 0..15: tn-tile (2 panels/XCD)
  const int y = r >> 1;                       // 0..31: tm-tile
  const int tn = x * 128;
  const int tm = y * 128;

  GEMM_MAIN_LOOP(A, Bm)

#pragma unroll
  for (int mi = 0; mi < 4; ++mi)
#pragma unroll
    for (int ni = 0; ni < 4; ++ni) {
      int col = tn + wn * 64 + ni * 16 + lc;
      int hh = col >> 6, d = col & 63;
      int m0 = tm + wm * 64 + mi * 16 + lr * 4;
      int bb = m0 >> 11, s = m0 & 2047;
      u16x4 v = { b16(acc[mi][ni][0]), b16(acc[mi][ni][1]),
                  b16(acc[mi][ni][2]), b16(acc[mi][ni][3]) };
      *(u16x4*)(vt + (((size_t)bb * NHEADS + hh) * 64 + d) * S_LEN + s) = v;
    }
}

// ---------------- output projection GEMM (128^2, XCD-swizzled) ----------
__global__ __launch_bounds__(256)
void gemm_out(const u16* __restrict__ A, const u16* __restrict__ Bm,
              float* __restrict__ C)
{
  __shared__ u16 sA[128 * 64];
  __shared__ u16 sB[128 * 64];
  const int tid  = threadIdx.x;
  const int lane = tid & 63;
  const int wid  = tid >> 6;
  const int wm   = wid >> 1, wn = wid & 1;
  const int lc   = lane & 15, lr = lane >> 4;
  const int L = blockIdx.x;
  const int r = L >> 3;                       // 0..63
  const int x = (L & 7) * 2 + (r & 1);        // 0..15: tn-tile
  const int y = r >> 1;                       // 0..31: tm-tile
  const int tn = x * 128;
  const int tm = y * 128;

  GEMM_MAIN_LOOP(A, Bm)

#pragma unroll
  for (int mi = 0; mi < 4; ++mi)
#pragma unroll
    for (int ni = 0; ni < 4; ++ni)
#pragma unroll
      for (int j = 0; j < 4; ++j) {
        int rr2 = tm + wm * 64 + mi * 16 + lr * 4 + j;
        int c = tn + wn * 64 + ni * 16 + lc;
        C[(size_t)rr2 * DMODEL + c] = acc[mi][ni][j];
      }
}

// ---------------- fused causal attention (R8 structure, verbatim) --------
__global__ __launch_bounds__(512, 6)
void attn_kernel(const u16* __restrict__ Q, const u16* __restrict__ K,
                 const u16* __restrict__ V, const u16* __restrict__ bias16,
                 const float* __restrict__ offg, u16* __restrict__ O)
{
  __shared__ __align__(16) u16 sK[2][64 * 64];
  __shared__ __align__(16) u16 sV[2][64 * 64];
  __shared__ __align__(16) u16 sP[8][16 * 72];
  __shared__ __align__(8)  u16 sBiasT[1152];

  const int tid = threadIdx.x, lane = tid & 63, wid = tid >> 6;
  const int lc = lane & 15, lr = lane >> 4;
  const int L  = blockIdx.x;
  const int p  = 15 - (L >> 6);
  const int bh = L & 63;
  const int h  = bh & 31;
  const int b  = bh >> 5;
  const int qw = p * 128 + wid * 16;
  const int nt = 2 * p + 2;

  for (int i = tid; i < 1152; i += 512) {
    int dd = i - 64;
    sBiasT[i] = (dd >= 0 && dd < BIAS_LEN) ? bias16[h * BIAS_LEN + dd] : (u16)0;
  }
  const float off = offg[h] * LOG2E;

  const u16* qp = Q + ((size_t)bh * S_LEN + qw + lc) * 64;
  bf16x8 aq0 = *(const bf16x8*)(qp + lr * 8);
  bf16x8 aq1 = *(const bf16x8*)(qp + 32 + lr * 8);

  const int srow = tid >> 3;
  const int sch  = (tid & 7) ^ (srow & 7);
  const u16* kSrc = K + ((size_t)bh * S_LEN + srow) * 64 + sch * 8;
  const u16* vSrc = V + ((size_t)bh * 64 + srow) * S_LEN + sch * 8;

  int offK[4][2], offV[2][4];
#pragma unroll
  for (int f = 0; f < 4; ++f) {
    int row = f * 16 + lc;
    offK[f][0] = row * 128 + ((lr) ^ (row & 7)) * 16;
    offK[f][1] = row * 128 + ((4 + lr) ^ (row & 7)) * 16;
  }
#pragma unroll
  for (int kk = 0; kk < 2; ++kk)
#pragma unroll
    for (int f2 = 0; f2 < 4; ++f2) {
      int drow = f2 * 16 + lc;
      offV[kk][f2] = drow * 128 + ((kk * 4 + lr) ^ (drow & 7)) * 16;
    }

  float lsum = 0.0f;
  f32x4 o[4] = {};

  gload16(kSrc, (char*)sK[0] + tid * 16);
  gload16(vSrc, (char*)sV[0] + tid * 16);
  __syncthreads();

  for (int t = 0; t < nt; ++t) {
    const int cur = t & 1;
    if (t + 1 < nt) {
      gload16(kSrc + (size_t)(t + 1) * 4096, (char*)sK[cur ^ 1] + tid * 16);
      gload16(vSrc + (t + 1) * 64,           (char*)sV[cur ^ 1] + tid * 16);
    }

    const int dqt = qw - t * 64;
    if (dqt >= 0) {
      const int db = dqt + lc;
      const bool inband = (dqt < 1088);
      f32x4 sc[4];
      __builtin_amdgcn_s_setprio(1);
#pragma unroll
      for (int f = 0; f < 4; ++f) {
        f32x4 z;
        if (inband) {
          const int ib = db + 64 - lr * 4 - f * 16;
#pragma unroll
          for (int j = 0; j < 4; ++j)
            z[j] = __uint_as_float((uint32_t)sBiasT[ib - j] << 16);
        } else {
          z[0] = z[1] = z[2] = z[3] = 0.0f;
        }
        bf16x8 k0 = *(const bf16x8*)((const char*)sK[cur] + offK[f][0]);
        bf16x8 k1 = *(const bf16x8*)((const char*)sK[cur] + offK[f][1]);
        z     = __builtin_amdgcn_mfma_f32_16x16x32_bf16(k0, aq0, z, 0, 0, 0);
        sc[f] = __builtin_amdgcn_mfma_f32_16x16x32_bf16(k1, aq1, z, 0, 0, 0);
      }
      __builtin_amdgcn_s_setprio(0);

      float pvv[4][4];
      if (dqt < 64) {
#pragma unroll
        for (int f = 0; f < 4; ++f)
#pragma unroll
          for (int j = 0; j < 4; ++j) {
            int dd = db - (f * 16 + lr * 4 + j);
            pvv[f][j] = (dd >= 0) ? sc[f][j] : -1e30f;
          }
      } else {
#pragma unroll
        for (int f = 0; f < 4; ++f)
#pragma unroll
          for (int j = 0; j < 4; ++j) pvv[f][j] = sc[f][j];
      }
#pragma unroll
      for (int f = 0; f < 4; ++f)
#pragma unroll
        for (int j = 0; j < 4; ++j) {
          float pe = exp2f(pvv[f][j]);
          pvv[f][j] = pe;
          lsum += pe;
        }

      u16* myP = sP[wid];
#pragma unroll
      for (int f = 0; f < 4; ++f) {
        u16x4 w = { b16(pvv[f][0]), b16(pvv[f][1]), b16(pvv[f][2]), b16(pvv[f][3]) };
        *(u16x4*)(myP + lc * 72 + f * 16 + lr * 4) = w;
      }
      asm volatile("s_waitcnt lgkmcnt(0)" ::: "memory");
      __builtin_amdgcn_sched_barrier(0);
      bf16x8 ap0 = *(const bf16x8*)(myP + lc * 72 + lr * 8);
      bf16x8 ap1 = *(const bf16x8*)(myP + lc * 72 + 32 + lr * 8);
      __builtin_amdgcn_s_setprio(1);
#pragma unroll
      for (int f2 = 0; f2 < 4; ++f2) {
        bf16x8 bv = *(const bf16x8*)((const char*)sV[cur] + offV[0][f2]);
        o[f2] = __builtin_amdgcn_mfma_f32_16x16x32_bf16(ap0, bv, o[f2], 0, 0, 0);
      }
#pragma unroll
      for (int f2 = 0; f2 < 4; ++f2) {
        bf16x8 bv = *(const bf16x8*)((const char*)sV[cur] + offV[1][f2]);
        o[f2] = __builtin_amdgcn_mfma_f32_16x16x32_bf16(ap1, bv, o[f2], 0, 0, 0);
      }
      __builtin_amdgcn_s_setprio(0);
    }
    __syncthreads();
  }

  lsum += __shfl_xor(lsum, 16, 64);
  lsum += __shfl_xor(lsum, 32, 64);
  lsum += exp2f(off);
  float ls[4];
#pragma unroll
  for (int j = 0; j < 4; ++j) ls[j] = 1.0f / __shfl(lsum, lr * 4 + j, 64);
#pragma unroll
  for (int f2 = 0; f2 < 4; ++f2)
#pragma unroll
    for (int j = 0; j < 4; ++j) {
      int i = qw + lr * 4 + j;
      int d = f2 * 16 + lc;
      size_t addr = (((size_t)(b * S_LEN + i)) * NHEADS + h) * 64 + d;
      O[addr] = b16(o[f2][j] * ls[j]);
    }
}

// ---------------- launcher ----------------
extern "C" void kernel_launch(void* const* d_in, const int* in_sizes, int n_in,
                              void* d_out, int out_size, void* d_ws, size_t ws_size,
                              hipStream_t stream)
{
  const float* hs   = (const float*)d_in[0];
  const float* Wq   = (const float*)d_in[1];
  const float* Wk   = (const float*)d_in[2];
  const float* Wv   = (const float*)d_in[3];
  const float* Wo   = (const float*)d_in[4];
  const float* bias = (const float*)d_in[5];
  const float* off  = (const float*)d_in[6];

  char* p = (char*)d_ws;
  u16* hs_b = (u16*)p; p += (size_t)MROWS * DMODEL * 2;
  u16* wq_b = (u16*)p; p += (size_t)DMODEL * DMODEL * 2;   // wq..wo contiguous
  u16* wk_b = (u16*)p; p += (size_t)DMODEL * DMODEL * 2;
  u16* wv_b = (u16*)p; p += (size_t)DMODEL * DMODEL * 2;
  u16* wo_b = (u16*)p; p += (size_t)DMODEL * DMODEL * 2;
  u16* qf   = (u16*)p; p += (size_t)MROWS * DMODEL * 2;
  u16* kf   = (u16*)p; p += (size_t)MROWS * DMODEL * 2;
  u16* vt   = (u16*)p; p += (size_t)MROWS * DMODEL * 2;
  u16* att  = (u16*)p; p += (size_t)MROWS * DMODEL * 2;
  float* ct = (float*)p; p += (size_t)S_LEN * 32 * 4;
  float* st = (float*)p; p += (size_t)S_LEN * 32 * 4;
  u16* b16t = (u16*)p; p += (size_t)NHEADS * BIAS_LEN * 2;
  (void)ws_size; (void)in_sizes; (void)n_in; (void)out_size;
  (void)wk_b;

  prep_all<<<dim3(24960), 256, 0, stream>>>(hs, Wq, Wk, Wv, Wo, bias,
                                            hs_b, wq_b, ct, st, b16t);
  gemm_qk8<<<dim3(256), 512, 0, stream>>>(hs_b, wq_b, qf, kf, ct, st);
  gemm_v<<<dim3(512), 256, 0, stream>>>(hs_b, wv_b, vt);
  attn_kernel<<<dim3(16 * 64), 512, 0, stream>>>(qf, kf, vt, b16t, off, att);
  gemm_out<<<dim3(512), 256, 0, stream>>>(att, wo_b, (float*)d_out);
}

// Round 15
// 268.085 us; speedup vs baseline: 1.0112x; 1.0112x over previous
//
#include <hip/hip_runtime.h>
#include <hip/hip_bf16.h>
#include <stdint.h>

typedef __bf16 bf16x8 __attribute__((ext_vector_type(8)));
typedef float f32x4 __attribute__((ext_vector_type(4)));
typedef unsigned short u16;
typedef u16 u16x4 __attribute__((ext_vector_type(4)));
typedef u16 u16x8 __attribute__((ext_vector_type(8)));

#define S_LEN 2048
#define DMODEL 2048
#define NHEADS 32
#define BATCH 2
#define MROWS (BATCH * S_LEN)   // 4096
#define BIAS_LEN 1024
#define LOG2E 1.44269504088896f

__device__ __forceinline__ u16 b16(float f) {
  union { __bf16 h; u16 u; } cv; cv.h = (__bf16)f; return cv.u;
}

__device__ __forceinline__ void gload16(const void* g, void* l) {
  __builtin_amdgcn_global_load_lds(
      (const __attribute__((address_space(1))) uint32_t*)g,
      (__attribute__((address_space(3))) uint32_t*)l, 16, 0, 0);
}

// ---------------- fused prep: hs->bf16, 4xW->bf16, rope tables, bias ------
__global__ __launch_bounds__(256)
void prep_all(const float* __restrict__ hs,
              const float* __restrict__ w0, const float* __restrict__ w1,
              const float* __restrict__ w2, const float* __restrict__ w3,
              const float* __restrict__ bias,
              u16* __restrict__ hs_b, u16* __restrict__ w_b,
              float* __restrict__ ct, float* __restrict__ st,
              u16* __restrict__ b16t)
{
  const int blk = blockIdx.x;
  if (blk < 8192) {                      // hs: 8M f32 -> bf16
    int i = (blk * 256 + threadIdx.x) * 4;
    float4 v = *(const float4*)(hs + i);
    u16x4 o = { b16(v.x), b16(v.y), b16(v.z), b16(v.w) };
    *(u16x4*)(hs_b + i) = o;
  } else if (blk < 24576) {              // 4 weight matrices
    int r = blk - 8192;
    int which = r >> 12;
    const float* src = (which == 0) ? w0 : (which == 1) ? w1
                     : (which == 2) ? w2 : w3;
    int i = ((r & 4095) * 256 + threadIdx.x) * 4;
    float4 v = *(const float4*)(src + i);
    u16x4 o = { b16(v.x), b16(v.y), b16(v.z), b16(v.w) };
    *(u16x4*)(w_b + (size_t)which * DMODEL * DMODEL + i) = o;
  } else if (blk < 24832) {              // rope cos/sin [S][32]
    int idx = (blk - 24576) * 256 + threadIdx.x;
    int s = idx >> 5, d = idx & 31;
    float inv = exp2f((float)d * (-13.287712379549449f / 32.0f));
    float a = (float)s * inv;
    ct[idx] = cosf(a);
    st[idx] = sinf(a);
  } else {                               // bias -> bf16 * log2e
    int i = (blk - 24832) * 256 + threadIdx.x;
    b16t[i] = b16(bias[i] * LOG2E);
  }
}

// ================= 8-phase 256x256 Q+K GEMM (R13 version, best) ===========
#define NT 32   // K tiles = 2048/64

#define STG_A(buf, h, t) { \
    gload16(aS0 + (size_t)(h) * 128 * DMODEL + (t) * 64, (char*)sA[buf][h] + tid * 16); \
    gload16(aS0 + (size_t)((h) * 128 + 64) * DMODEL + (t) * 64, (char*)sA[buf][h] + (512 + tid) * 16); }
#define STG_B(buf, h, t) { \
    gload16(bS0 + (size_t)(h) * 128 * DMODEL + (t) * 64, (char*)sB[buf][h] + tid * 16); \
    gload16(bS0 + (size_t)((h) * 128 + 64) * DMODEL + (t) * 64, (char*)sB[buf][h] + (512 + tid) * 16); }
#define LOAD_B(b, kk) { _Pragma("unroll") \
    for (int ni = 0; ni < 4; ++ni) \
      bq[ni] = *(const bf16x8*)((const char*)sB[b][wn >> 1] + offB[ni][kk]); }
#define LOAD_A(b, q, kk) { _Pragma("unroll") \
    for (int mi = 0; mi < 4; ++mi) \
      af[mi] = *(const bf16x8*)((const char*)sA[b][wm] + offA[q][mi][kk]); }
#define MFMA16(q) { __builtin_amdgcn_s_setprio(1); \
    _Pragma("unroll") for (int mi = 0; mi < 4; ++mi) \
      _Pragma("unroll") for (int ni = 0; ni < 4; ++ni) \
        acc[(q) * 4 + mi][ni] = __builtin_amdgcn_mfma_f32_16x16x32_bf16( \
            af[mi], bq[ni], acc[(q) * 4 + mi][ni], 0, 0, 0); \
    __builtin_amdgcn_s_setprio(0); }
#define LGKM { asm volatile("s_waitcnt lgkmcnt(0)" ::: "memory"); \
               __builtin_amdgcn_sched_barrier(0); }
#define BARR { __builtin_amdgcn_s_barrier(); __builtin_amdgcn_sched_barrier(0); }
#define VM2 { asm volatile("s_waitcnt vmcnt(2)" ::: "memory"); \
              __builtin_amdgcn_sched_barrier(0); }
#define VM0 { asm volatile("s_waitcnt vmcnt(0)" ::: "memory"); \
              __builtin_amdgcn_sched_barrier(0); }

__global__ __launch_bounds__(512, 2)
void gemm_qk8(const u16* __restrict__ A, const u16* __restrict__ W,
              u16* __restrict__ qf, u16* __restrict__ kf,
              const float* __restrict__ ctab, const float* __restrict__ stab)
{
  __shared__ u16 sA[2][2][128 * 64];
  __shared__ u16 sB[2][2][128 * 64];
  const int tid = threadIdx.x, lane = tid & 63, wid = tid >> 6;
  const int wm = wid >> 2, wn = wid & 3;     // 2M x 4N wave grid
  const int lc = lane & 15, lr = lane >> 4;
  const int L = blockIdx.x;
  const int which = L >> 7;                   // 0=q 1=k
  const int rr = L & 127;
  const int tmi = rr >> 3, tni = rr & 7;      // tni == L%8: B-panel L2 pin
  const size_t tm = (size_t)tmi * 256, tn = (size_t)tni * 256;
  const u16* Bm = W + (size_t)which * DMODEL * DMODEL;

  const int r0 = tid >> 3, c0 = (tid & 7) ^ (r0 & 7);
  const u16* aS0 = A  + (tm + r0) * DMODEL + c0 * 8;
  const u16* bS0 = Bm + (tn + r0) * DMODEL + c0 * 8;

  int offA[2][4][2], offB[4][2];
#pragma unroll
  for (int q = 0; q < 2; ++q)
#pragma unroll
    for (int mi = 0; mi < 4; ++mi) {
      int row = q * 64 + mi * 16 + lc;
#pragma unroll
      for (int kk = 0; kk < 2; ++kk)
        offA[q][mi][kk] = row * 128 + ((kk * 4 + lr) ^ (row & 7)) * 16;
    }
#pragma unroll
  for (int ni = 0; ni < 4; ++ni) {
    int row = (wn & 1) * 64 + ni * 16 + lc;
#pragma unroll
    for (int kk = 0; kk < 2; ++kk)
      offB[ni][kk] = row * 128 + ((kk * 4 + lr) ^ (row & 7)) * 16;
  }

  f32x4 acc[8][4] = {};
  bf16x8 af[4], bq[4];

  STG_B(0, 0, 0); STG_B(0, 1, 0); STG_A(0, 0, 0); STG_A(0, 1, 0); STG_B(1, 0, 1);
  VM2; BARR;

  for (int i = 0; i < NT / 2; ++i) {
    const int t1 = 2 * i + 1, t2 = 2 * i + 2, t3 = 2 * i + 3;
    LOAD_B(0, 0); LOAD_A(0, 0, 0); STG_B(1, 1, t1); LGKM; MFMA16(0);
    LOAD_A(0, 1, 0); STG_A(1, 0, t1); LGKM; MFMA16(1);
    LOAD_B(0, 1); LOAD_A(0, 0, 1); STG_A(1, 1, t1); LGKM; MFMA16(0);
    BARR;                                   // end-p3: B(t0) fully consumed
    LOAD_A(0, 1, 1); if (t2 < NT) STG_B(0, 0, t2); LGKM; MFMA16(1);
    if (t2 < NT) { VM2; } else { VM0; }     // tile t1 landed
    BARR;                                   // end-p4: A(t0) consumed
    LOAD_B(1, 0); LOAD_A(1, 0, 0); if (t2 < NT) STG_B(0, 1, t2); LGKM; MFMA16(0);
    LOAD_A(1, 1, 0); if (t2 < NT) STG_A(0, 0, t2); LGKM; MFMA16(1);
    LOAD_B(1, 1); LOAD_A(1, 0, 1); if (t2 < NT) STG_A(0, 1, t2); LGKM; MFMA16(0);
    BARR;                                   // end-p7: B(t1) consumed
    LOAD_A(1, 1, 1); if (t3 < NT) STG_B(1, 0, t3); LGKM; MFMA16(1);
    if (t3 < NT) { VM2; } else { VM0; }     // tile t2 landed
    BARR;                                   // end-p8: A(t1) consumed
  }

  // epilogue: RoPE (q also * 0.125*log2e), store [B,H,S,D] bf16
  u16* C = (which == 0) ? qf : kf;
  const float scl = (which == 0) ? 0.125f * LOG2E : 1.0f;
#pragma unroll
  for (int q = 0; q < 2; ++q)
#pragma unroll
    for (int mi = 0; mi < 4; ++mi)
#pragma unroll
      for (int ni = 0; ni < 2; ++ni)
#pragma unroll
        for (int j = 0; j < 4; ++j) {
          int col = (int)tn + wn * 64 + ni * 16 + lc;
          int hh = col >> 6, dl = col & 63;     // dl in [0,32)
          int r = (int)tm + wm * 128 + q * 64 + mi * 16 + lr * 4 + j;
          int bb = r >> 11, s = r & 2047;
          float x1 = acc[q * 4 + mi][ni][j], x2 = acc[q * 4 + mi][ni + 2][j];
          float cv = ctab[s * 32 + dl], sv = stab[s * 32 + dl];
          float o1 = (x1 * cv - x2 * sv) * scl;
          float o2 = (x1 * sv + x2 * cv) * scl;
          size_t base = (((size_t)bb * NHEADS + hh) * S_LEN + s) * 64 + dl;
          C[base]      = b16(o1);
          C[base + 32] = b16(o2);
        }
}

// ======== shared 128^2 GEMM main-loop macro (m97 structure) ========
#define GEMM_MAIN_LOOP(Aptr, Bptr)                                            \
  f32x4 acc[4][4] = {};                                                       \
  const u16* aS[4]; const u16* bS[4];                                         \
  _Pragma("unroll")                                                           \
  for (int it = 0; it < 4; ++it) {                                            \
    int u = it * 256 + tid;                                                   \
    int row = u >> 3;                                                         \
    int ch  = (u & 7) ^ (row & 7);                                            \
    aS[it] = (Aptr) + (size_t)(tm + row) * DMODEL + ch * 8;                   \
    bS[it] = (Bptr) + (size_t)(tn + row) * DMODEL + ch * 8;                   \
  }                                                                           \
  for (int k0 = 0; k0 < DMODEL; k0 += 64) {                                   \
    __syncthreads();                                                          \
    _Pragma("unroll")                                                         \
    for (int it = 0; it < 4; ++it) {                                          \
      int u = it * 256 + tid;                                                 \
      gload16(aS[it] + k0, (char*)sA + u * 16);                               \
      gload16(bS[it] + k0, (char*)sB + u * 16);                               \
    }                                                                         \
    __syncthreads();                                                          \
    _Pragma("unroll")                                                         \
    for (int kk = 0; kk < 2; ++kk) {                                          \
      bf16x8 af[4], bq[4];                                                    \
      _Pragma("unroll")                                                       \
      for (int mi = 0; mi < 4; ++mi) {                                        \
        int row = wm * 64 + mi * 16 + lc;                                     \
        int ch  = (kk * 4 + lr) ^ (row & 7);                                  \
        af[mi] = *(const bf16x8*)((const char*)sA + row * 128 + ch * 16);     \
      }                                                                       \
      _Pragma("unroll")                                                       \
      for (int ni = 0; ni < 4; ++ni) {                                        \
        int row = wn * 64 + ni * 16 + lc;                                     \
        int ch  = (kk * 4 + lr) ^ (row & 7);                                  \
        bq[ni] = *(const bf16x8*)((const char*)sB + row * 128 + ch * 16);     \
      }                                                                       \
      _Pragma("unroll")                                                       \
      for (int mi = 0; mi < 4; ++mi)                                          \
        _Pragma("unroll")                                                     \
        for (int ni = 0; ni < 4; ++ni)                                        \
          acc[mi][ni] = __builtin_amdgcn_mfma_f32_16x16x32_bf16(              \
              af[mi], bq[ni], acc[mi][ni], 0, 0, 0);                          \
    }                                                                         \
  }

// ---------------- V projection GEMM (128^2): coalesced v^T store ----------
// Epilogue stages the wave's 64x64 acc tile through LDS (reusing sA after a
// __syncthreads; 4KB/wave/half, 8B-chunk XOR swizzle) and stores v^T rows as
// contiguous 128B (8 lanes x u16x8) instead of 16 scattered 8B stores.
__global__ __launch_bounds__(256)
void gemm_v(const u16* __restrict__ A, const u16* __restrict__ Bm,
            u16* __restrict__ vt)
{
  __shared__ u16 sA[128 * 64];
  __shared__ u16 sB[128 * 64];
  const int tid  = threadIdx.x;
  const int lane = tid & 63;
  const int wid  = tid >> 6;
  const int wm   = wid >> 1, wn = wid & 1;
  const int lc   = lane & 15, lr = lane >> 4;
  const int L = blockIdx.x;                   // 512 blocks
  const int r = L >> 3;                       // 0..63
  const int x = (L & 7) * 2 + (r & 1);        // 0..15: tn-tile (2 panels/XCD)
  const int y = r >> 1;                       // 0..31: tm-tile
  const int tn = x * 128;
  const int tm = y * 128;

  GEMM_MAIN_LOOP(A, Bm)

  __syncthreads();                       // all waves done with sA/sB frags
  u16* T = sA + wid * 2048;              // 4KB per wave (32 rows x 128B)
  const int hh = (tn + wn * 64) >> 6;    // wave's head (64-col aligned)
  const int m0w = tm + wm * 64;          // wave's 64 contiguous s rows
  const int bbv = m0w >> 11;
  const int sb  = m0w & 2047;

#pragma unroll
  for (int half = 0; half < 2; ++half) {
    // write: 8 x u16x4 per lane, 8B-chunk XOR swizzle (2-way banks = free)
#pragma unroll
    for (int mi = 0; mi < 4; ++mi)
#pragma unroll
      for (int nn = 0; nn < 2; ++nn) {
        int ni = half * 2 + nn;
        int dl = nn * 16 + lc;            // 0..31 row in T
        int c8s = (mi * 4 + lr) ^ ((dl & 7) << 1);
        u16x4 w = { b16(acc[mi][ni][0]), b16(acc[mi][ni][1]),
                    b16(acc[mi][ni][2]), b16(acc[mi][ni][3]) };
        *(u16x4*)((char*)T + dl * 128 + c8s * 8) = w;
      }
    asm volatile("s_waitcnt lgkmcnt(0)" ::: "memory");
    __builtin_amdgcn_sched_barrier(0);
    // read rows + coalesced global store (8 lanes cover one 128B row)
#pragma unroll
    for (int it = 0; it < 4; ++it) {
      int rl = it * 8 + (lane >> 3);      // 0..31
      int c16 = (lane & 7) ^ (rl & 7);
      u16x8 v = *(const u16x8*)((const char*)T + rl * 128 + c16 * 16);
      int d = half * 32 + rl;
      size_t addr = (((size_t)bbv * NHEADS + hh) * 64 + d) * S_LEN
                    + sb + (lane & 7) * 8;
      *(u16x8*)(vt + addr) = v;
    }
    if (half == 0) {
      asm volatile("s_waitcnt lgkmcnt(0)" ::: "memory");
      __builtin_amdgcn_sched_barrier(0);
    }
  }
}

// ---------------- output projection GEMM (128^2, XCD-swizzled) ----------
__global__ __launch_bounds__(256)
void gemm_out(const u16* __restrict__ A, const u16* __restrict__ Bm,
              float* __restrict__ C)
{
  __shared__ u16 sA[128 * 64];
  __shared__ u16 sB[128 * 64];
  const int tid  = threadIdx.x;
  const int lane = tid & 63;
  const int wid  = tid >> 6;
  const int wm   = wid >> 1, wn = wid & 1;
  const int lc   = lane & 15, lr = lane >> 4;
  const int L = blockIdx.x;
  const int r = L >> 3;                       // 0..63
  const int x = (L & 7) * 2 + (r & 1);        // 0..15: tn-tile
  const int y = r >> 1;                       // 0..31: tm-tile
  const int tn = x * 128;
  const int tm = y * 128;

  GEMM_MAIN_LOOP(A, Bm)

#pragma unroll
  for (int mi = 0; mi < 4; ++mi)
#pragma unroll
    for (int ni = 0; ni < 4; ++ni)
#pragma unroll
      for (int j = 0; j < 4; ++j) {
        int rr2 = tm + wm * 64 + mi * 16 + lr * 4 + j;
        int c = tn + wn * 64 + ni * 16 + lc;
        C[(size_t)rr2 * DMODEL + c] = acc[mi][ni][j];
      }
}

// ---------------- fused causal attention (R8 structure) ------------------
// Only change this round: pairwise-tree lsum (breaks the 16-deep serial
// FP-add chain; ~5-deep).  Everything else verbatim.
__global__ __launch_bounds__(512, 6)
void attn_kernel(const u16* __restrict__ Q, const u16* __restrict__ K,
                 const u16* __restrict__ V, const u16* __restrict__ bias16,
                 const float* __restrict__ offg, u16* __restrict__ O)
{
  __shared__ __align__(16) u16 sK[2][64 * 64];
  __shared__ __align__(16) u16 sV[2][64 * 64];
  __shared__ __align__(16) u16 sP[8][16 * 72];
  __shared__ __align__(8)  u16 sBiasT[1152];

  const int tid = threadIdx.x, lane = tid & 63, wid = tid >> 6;
  const int lc = lane & 15, lr = lane >> 4;
  const int L  = blockIdx.x;
  const int p  = 15 - (L >> 6);
  const int bh = L & 63;
  const int h  = bh & 31;
  const int b  = bh >> 5;
  const int qw = p * 128 + wid * 16;
  const int nt = 2 * p + 2;

  for (int i = tid; i < 1152; i += 512) {
    int dd = i - 64;
    sBiasT[i] = (dd >= 0 && dd < BIAS_LEN) ? bias16[h * BIAS_LEN + dd] : (u16)0;
  }
  const float off = offg[h] * LOG2E;

  const u16* qp = Q + ((size_t)bh * S_LEN + qw + lc) * 64;
  bf16x8 aq0 = *(const bf16x8*)(qp + lr * 8);
  bf16x8 aq1 = *(const bf16x8*)(qp + 32 + lr * 8);

  const int srow = tid >> 3;
  const int sch  = (tid & 7) ^ (srow & 7);
  const u16* kSrc = K + ((size_t)bh * S_LEN + srow) * 64 + sch * 8;
  const u16* vSrc = V + ((size_t)bh * 64 + srow) * S_LEN + sch * 8;

  int offK[4][2], offV[2][4];
#pragma unroll
  for (int f = 0; f < 4; ++f) {
    int row = f * 16 + lc;
    offK[f][0] = row * 128 + ((lr) ^ (row & 7)) * 16;
    offK[f][1] = row * 128 + ((4 + lr) ^ (row & 7)) * 16;
  }
#pragma unroll
  for (int kk = 0; kk < 2; ++kk)
#pragma unroll
    for (int f2 = 0; f2 < 4; ++f2) {
      int drow = f2 * 16 + lc;
      offV[kk][f2] = drow * 128 + ((kk * 4 + lr) ^ (drow & 7)) * 16;
    }

  float lsum = 0.0f;
  f32x4 o[4] = {};

  gload16(kSrc, (char*)sK[0] + tid * 16);
  gload16(vSrc, (char*)sV[0] + tid * 16);
  __syncthreads();

  for (int t = 0; t < nt; ++t) {
    const int cur = t & 1;
    if (t + 1 < nt) {
      gload16(kSrc + (size_t)(t + 1) * 4096, (char*)sK[cur ^ 1] + tid * 16);
      gload16(vSrc + (t + 1) * 64,           (char*)sV[cur ^ 1] + tid * 16);
    }

    const int dqt = qw - t * 64;
    if (dqt >= 0) {
      const int db = dqt + lc;
      const bool inband = (dqt < 1088);
      f32x4 sc[4];
      __builtin_amdgcn_s_setprio(1);
#pragma unroll
      for (int f = 0; f < 4; ++f) {
        f32x4 z;
        if (inband) {
          const int ib = db + 64 - lr * 4 - f * 16;
#pragma unroll
          for (int j = 0; j < 4; ++j)
            z[j] = __uint_as_float((uint32_t)sBiasT[ib - j] << 16);
        } else {
          z[0] = z[1] = z[2] = z[3] = 0.0f;
        }
        bf16x8 k0 = *(const bf16x8*)((const char*)sK[cur] + offK[f][0]);
        bf16x8 k1 = *(const bf16x8*)((const char*)sK[cur] + offK[f][1]);
        z     = __builtin_amdgcn_mfma_f32_16x16x32_bf16(k0, aq0, z, 0, 0, 0);
        sc[f] = __builtin_amdgcn_mfma_f32_16x16x32_bf16(k1, aq1, z, 0, 0, 0);
      }
      __builtin_amdgcn_s_setprio(0);

      float pvv[4][4];
      if (dqt < 64) {
#pragma unroll
        for (int f = 0; f < 4; ++f)
#pragma unroll
          for (int j = 0; j < 4; ++j) {
            int dd = db - (f * 16 + lr * 4 + j);
            pvv[f][j] = (dd >= 0) ? sc[f][j] : -1e30f;
          }
      } else {
#pragma unroll
        for (int f = 0; f < 4; ++f)
#pragma unroll
          for (int j = 0; j < 4; ++j) pvv[f][j] = sc[f][j];
      }
      float sf[4];
#pragma unroll
      for (int f = 0; f < 4; ++f) {
        float p0 = exp2f(pvv[f][0]); pvv[f][0] = p0;
        float p1 = exp2f(pvv[f][1]); pvv[f][1] = p1;
        float p2 = exp2f(pvv[f][2]); pvv[f][2] = p2;
        float p3 = exp2f(pvv[f][3]); pvv[f][3] = p3;
        sf[f] = (p0 + p1) + (p2 + p3);
      }
      lsum += (sf[0] + sf[1]) + (sf[2] + sf[3]);

      u16* myP = sP[wid];
#pragma unroll
      for (int f = 0; f < 4; ++f) {
        u16x4 w = { b16(pvv[f][0]), b16(pvv[f][1]), b16(pvv[f][2]), b16(pvv[f][3]) };
        *(u16x4*)(myP + lc * 72 + f * 16 + lr * 4) = w;
      }
      asm volatile("s_waitcnt lgkmcnt(0)" ::: "memory");
      __builtin_amdgcn_sched_barrier(0);
      bf16x8 ap0 = *(const bf16x8*)(myP + lc * 72 + lr * 8);
      bf16x8 ap1 = *(const bf16x8*)(myP + lc * 72 + 32 + lr * 8);
      __builtin_amdgcn_s_setprio(1);
#pragma unroll
      for (int f2 = 0; f2 < 4; ++f2) {
        bf16x8 bv = *(const bf16x8*)((const char*)sV[cur] + offV[0][f2]);
        o[f2] = __builtin_amdgcn_mfma_f32_16x16x32_bf16(ap0, bv, o[f2], 0, 0, 0);
      }
#pragma unroll
      for (int f2 = 0; f2 < 4; ++f2) {
        bf16x8 bv = *(const bf16x8*)((const char*)sV[cur] + offV[1][f2]);
        o[f2] = __builtin_amdgcn_mfma_f32_16x16x32_bf16(ap1, bv, o[f2], 0, 0, 0);
      }
      __builtin_amdgcn_s_setprio(0);
    }
    __syncthreads();
  }

  lsum += __shfl_xor(lsum, 16, 64);
  lsum += __shfl_xor(lsum, 32, 64);
  lsum += exp2f(off);
  float ls[4];
#pragma unroll
  for (int j = 0; j < 4; ++j) ls[j] = 1.0f / __shfl(lsum, lr * 4 + j, 64);
#pragma unroll
  for (int f2 = 0; f2 < 4; ++f2)
#pragma unroll
    for (int j = 0; j < 4; ++j) {
      int i = qw + lr * 4 + j;
      int d = f2 * 16 + lc;
      size_t addr = (((size_t)(b * S_LEN + i)) * NHEADS + h) * 64 + d;
      O[addr] = b16(o[f2][j] * ls[j]);
    }
}

// ---------------- launcher ----------------
extern "C" void kernel_launch(void* const* d_in, const int* in_sizes, int n_in,
                              void* d_out, int out_size, void* d_ws, size_t ws_size,
                              hipStream_t stream)
{
  const float* hs   = (const float*)d_in[0];
  const float* Wq   = (const float*)d_in[1];
  const float* Wk   = (const float*)d_in[2];
  const float* Wv   = (const float*)d_in[3];
  const float* Wo   = (const float*)d_in[4];
  const float* bias = (const float*)d_in[5];
  const float* off  = (const float*)d_in[6];

  char* p = (char*)d_ws;
  u16* hs_b = (u16*)p; p += (size_t)MROWS * DMODEL * 2;
  u16* wq_b = (u16*)p; p += (size_t)DMODEL * DMODEL * 2;   // wq..wo contiguous
  u16* wk_b = (u16*)p; p += (size_t)DMODEL * DMODEL * 2;
  u16* wv_b = (u16*)p; p += (size_t)DMODEL * DMODEL * 2;
  u16* wo_b = (u16*)p; p += (size_t)DMODEL * DMODEL * 2;
  u16* qf   = (u16*)p; p += (size_t)MROWS * DMODEL * 2;
  u16* kf   = (u16*)p; p += (size_t)MROWS * DMODEL * 2;
  u16* vt   = (u16*)p; p += (size_t)MROWS * DMODEL * 2;
  u16* att  = (u16*)p; p += (size_t)MROWS * DMODEL * 2;
  float* ct = (float*)p; p += (size_t)S_LEN * 32 * 4;
  float* st = (float*)p; p += (size_t)S_LEN * 32 * 4;
  u16* b16t = (u16*)p; p += (size_t)NHEADS * BIAS_LEN * 2;
  (void)ws_size; (void)in_sizes; (void)n_in; (void)out_size;
  (void)wk_b;

  prep_all<<<dim3(24960), 256, 0, stream>>>(hs, Wq, Wk, Wv, Wo, bias,
                                            hs_b, wq_b, ct, st, b16t);
  gemm_qk8<<<dim3(256), 512, 0, stream>>>(hs_b, wq_b, qf, kf, ct, st);
  gemm_v<<<dim3(512), 256, 0, stream>>>(hs_b, wv_b, vt);
  attn_kernel<<<dim3(16 * 64), 512, 0, stream>>>(qf, kf, vt, b16t, off, att);
  gemm_out<<<dim3(512), 256, 0, stream>>>(att, wo_b, (float*)d_out);
}